// Round 11
// baseline (134.660 us; speedup 1.0000x reference)
//
#include <hip/hip_runtime.h>
#include <math.h>

constexpr int BATCH  = 2;
constexpr int LSEQ   = 4096;
constexpr int DMODEL = 256;
constexpr int DINNER = 512;
constexpr int NST    = 16;              // d_state
constexpr int MROWS  = BATCH * LSEQ;    // 8192
constexpr int NCH    = 256;             // chunks per sequence
constexpr int TCH    = LSEQ / NCH;      // 16 steps per chunk
constexpr float LOG2E = 1.44269504088896f;
constexpr float LN2   = 0.69314718056f;

typedef __attribute__((ext_vector_type(8))) short bf16x8;
typedef __attribute__((ext_vector_type(4))) float f32x4;

__device__ __forceinline__ float fast_silu(float v) { return v / (1.f + __expf(-v)); }

__device__ __forceinline__ unsigned short f2bf(float f) {
  unsigned int u = __float_as_uint(f);
  u = (u + 0x7fffu + ((u >> 16) & 1u)) >> 16;   // RNE
  return (unsigned short)u;
}
__device__ __forceinline__ float bf2f(unsigned short u) {
  return __uint_as_float(((unsigned int)u) << 16);
}

// ---------------------------------------------------------------- transpose-cast W[K][N] -> Wt[N][K] bf16
__global__ __launch_bounds__(256) void k_castT(const float* __restrict__ W,
                                               unsigned short* __restrict__ Wt,
                                               int K, int N, int ktiles) {
  __shared__ float tile[32][33];
  const int bt = blockIdx.x;
  const int kt = bt % ktiles, nt = bt / ktiles;
  const int k0 = kt * 32, n0 = nt * 32;
  const int t = threadIdx.x;
  const int c = t & 31, r0 = t >> 5;
  #pragma unroll
  for (int it = 0; it < 4; ++it) {
    int r = r0 + it * 8;
    tile[r][c] = W[(size_t)(k0 + r) * N + n0 + c];
  }
  __syncthreads();
  #pragma unroll
  for (int it = 0; it < 4; ++it) {
    int cc = r0 + it * 8;
    Wt[(size_t)(n0 + cc) * K + k0 + c] = f2bf(tile[c][cc]);
  }
}

// ---------------------------------------------------------------- transpose-cast x_proj_w [512][48] -> [48][512] bf16
__global__ __launch_bounds__(256) void k_cast_xpw(const float* __restrict__ xpw,
                                                  unsigned short* __restrict__ xpT) {
  int idx = blockIdx.x * 256 + threadIdx.x;      // 48*512 = 24576
  int n = idx >> 9, k = idx & 511;
  xpT[n * 512 + k] = f2bf(xpw[k * 48 + n]);
}

// ---------------------------------------------------------------- precompute a2T[n][d] = -exp(A_log[d][n]) * log2e
__global__ __launch_bounds__(256) void k_prep_a2(const float* __restrict__ Alog,
                                                 float* __restrict__ a2T) {
  int idx = blockIdx.x * 256 + threadIdx.x;      // 16*512 = 8192
  int n = idx >> 9, d = idx & 511;
  a2T[idx] = -__expf(Alog[d * NST + n]) * LOG2E;
}

// ---------------------------------------------------------------- K1: xz = x @ in_proj_w (bf16 MFMA); u,z bf16
__global__ __launch_bounds__(256) void k_inproj(const float* __restrict__ X,
                                                const unsigned short* __restrict__ Wt,
                                                unsigned short* __restrict__ ub,
                                                unsigned short* __restrict__ zb) {
  __shared__ unsigned short As[128][40];
  __shared__ unsigned short Bs[128][40];
  const int t = threadIdx.x;
  const int m0 = (blockIdx.x & 63) * 128;
  const int n0 = (blockIdx.x >> 6) * 128;
  const int lane = t & 63, wid = t >> 6;
  const int hi = lane >> 4, l15 = lane & 15;
  const int wm = wid >> 1, wn = wid & 1;
  f32x4 zero = {0.f, 0.f, 0.f, 0.f};
  f32x4 acc[4][4];
  #pragma unroll
  for (int i = 0; i < 4; ++i)
    #pragma unroll
    for (int j = 0; j < 4; ++j) acc[i][j] = zero;

  for (int k0 = 0; k0 < DMODEL; k0 += 32) {
    __syncthreads();
    #pragma unroll
    for (int it = 0; it < 4; ++it) {              // A: fp32 -> bf16 during stage
      int v = it * 256 + t;
      int r = v >> 3, part = v & 7;
      float4 a = *(const float4*)(X + (size_t)(m0 + r) * 256 + k0 + part * 4);
      ushort4 o;
      o.x = f2bf(a.x); o.y = f2bf(a.y); o.z = f2bf(a.z); o.w = f2bf(a.w);
      *(ushort4*)(&As[r][part * 4]) = o;
    }
    #pragma unroll
    for (int it = 0; it < 2; ++it) {              // B: bf16 direct
      int v = it * 256 + t;
      int r = v >> 2, part = v & 3;
      *(float4*)(&Bs[r][part * 8]) = *(const float4*)(Wt + (size_t)(n0 + r) * 256 + k0 + part * 8);
    }
    __syncthreads();
    bf16x8 af[4], bfv[4];
    #pragma unroll
    for (int am = 0; am < 4; ++am) af[am] = *(const bf16x8*)(&As[wm * 64 + am * 16 + l15][hi * 8]);
    #pragma unroll
    for (int bn = 0; bn < 4; ++bn) bfv[bn] = *(const bf16x8*)(&Bs[wn * 64 + bn * 16 + l15][hi * 8]);
    #pragma unroll
    for (int am = 0; am < 4; ++am)
      #pragma unroll
      for (int bn = 0; bn < 4; ++bn)
        acc[am][bn] = __builtin_amdgcn_mfma_f32_16x16x32_bf16(af[am], bfv[bn], acc[am][bn], 0, 0, 0);
  }

  unsigned short* dst = (n0 < DINNER) ? ub : zb;
  const int nb = (n0 < DINNER) ? n0 : n0 - DINNER;
  #pragma unroll
  for (int am = 0; am < 4; ++am)
    #pragma unroll
    for (int j = 0; j < 4; ++j) {
      int m = m0 + wm * 64 + am * 16 + hi * 4 + j;
      #pragma unroll
      for (int bn = 0; bn < 4; ++bn) {
        int n = nb + wn * 64 + bn * 16 + l15;
        dst[(size_t)m * DINNER + n] = f2bf(acc[am][bn][j]);
      }
    }
}

// ---------------------------------------------------------------- K2: depthwise causal conv + SiLU -> bf16 (2 d/thread)
__global__ __launch_bounds__(256) void k_conv(const unsigned short* __restrict__ ub,
                                              const float* __restrict__ cw,
                                              const float* __restrict__ cb,
                                              unsigned short* __restrict__ ucb) {
  const int e2 = blockIdx.x * 256 + threadIdx.x;     // pair index
  const int idx = e2 * 2;                            // element index (even)
  const int d = idx & (DINNER - 1);
  const int m = idx >> 9;
  const int l = m & (LSEQ - 1);
  float a0 = cb[d], a1 = cb[d + 1];
  #pragma unroll
  for (int j = 0; j < 4; ++j) {
    int lj = l + j - 3;
    unsigned int p = (lj >= 0) ? *(const unsigned int*)(ub + idx + (j - 3) * DINNER) : 0u;
    float u0 = bf2f((unsigned short)(p & 0xffffu));
    float u1 = bf2f((unsigned short)(p >> 16));
    a0 = fmaf(u0, cw[d * 4 + j], a0);
    a1 = fmaf(u1, cw[(d + 1) * 4 + j], a1);
  }
  unsigned int o = (unsigned int)f2bf(fast_silu(a0)) | ((unsigned int)f2bf(fast_silu(a1)) << 16);
  *(unsigned int*)(ucb + idx) = o;
}

// ---------------------------------------------------------------- K3: dbl = uc @ x_proj_w via MFMA -> dt,B,C (fp32)
__global__ __launch_bounds__(128) void k_xprojm(const unsigned short* __restrict__ ucb,
                                                const unsigned short* __restrict__ xpT,
                                                float* __restrict__ dt_out,
                                                float* __restrict__ Bout,
                                                float* __restrict__ Cout) {
  __shared__ unsigned short As[32][136];
  __shared__ unsigned short Bs[48][136];
  const int t = threadIdx.x;
  const int m0 = blockIdx.x * 32;
  const int lane = t & 63, wid = t >> 6;     // 2 waves
  const int hi = lane >> 4, l15 = lane & 15;
  f32x4 zero = {0.f, 0.f, 0.f, 0.f};
  f32x4 acc[3] = {zero, zero, zero};

  for (int k0 = 0; k0 < DINNER; k0 += 128) {
    __syncthreads();
    #pragma unroll
    for (int it = 0; it < 4; ++it) {
      int v = it * 128 + t;
      int r = v >> 4, part = v & 15;
      *(float4*)(&As[r][part * 8]) = *(const float4*)(ucb + (size_t)(m0 + r) * 512 + k0 + part * 8);
    }
    #pragma unroll
    for (int it = 0; it < 6; ++it) {
      int v = it * 128 + t;
      int r = v >> 4, part = v & 15;
      *(float4*)(&Bs[r][part * 8]) = *(const float4*)(xpT + (size_t)r * 512 + k0 + part * 8);
    }
    __syncthreads();
    #pragma unroll
    for (int kk = 0; kk < 4; ++kk) {
      bf16x8 af = *(const bf16x8*)(&As[wid * 16 + l15][kk * 32 + hi * 8]);
      #pragma unroll
      for (int nf = 0; nf < 3; ++nf) {
        bf16x8 bv = *(const bf16x8*)(&Bs[nf * 16 + l15][kk * 32 + hi * 8]);
        acc[nf] = __builtin_amdgcn_mfma_f32_16x16x32_bf16(af, bv, acc[nf], 0, 0, 0);
      }
    }
  }
  #pragma unroll
  for (int j = 0; j < 4; ++j) {
    int m = m0 + wid * 16 + hi * 4 + j;
    dt_out[m * 16 + l15] = acc[0][j];
    Bout[m * 16 + l15]   = acc[1][j];
    Cout[m * 16 + l15]   = acc[2][j];
  }
}

// ---------------------------------------------------------------- K4a: scan pass 1: delta (bf16) + per-chunk (S bf16, dsum)
// block = fixed (b, c, d-half); ucb time-tile staged in LDS
__global__ __launch_bounds__(256) void k_scan1(const unsigned short* __restrict__ ucb,
                                               const float* __restrict__ dtin,
                                               const float* __restrict__ dtw,
                                               const float* __restrict__ dtb,
                                               const float* __restrict__ Bin,
                                               const float* __restrict__ a2T,
                                               unsigned short* __restrict__ delta_b,
                                               unsigned short* __restrict__ Ssum,
                                               float* __restrict__ Dsum) {
  const int t = threadIdx.x;
  const int d0 = (blockIdx.x & 1) * 256;
  const int rest = blockIdx.x >> 1;
  const int c = rest & (NCH - 1);
  const int b = rest >> 8;
  const int d = d0 + t;
  __shared__ float Bsh[TCH][NST];
  __shared__ float dtsh[TCH][NST];
  __shared__ unsigned short UC[TCH][256];
  const int rbase = (b * LSEQ + c * TCH) * DINNER + d0;
  {
    const int base = (b * LSEQ + c * TCH) * NST;
    ((float*)Bsh)[t]  = Bin[base + t];             // TCH*NST == 256
    ((float*)dtsh)[t] = dtin[base + t];
    #pragma unroll
    for (int it = 0; it < 2; ++it) {               // 16 rows x 256 ushort = 512 x 16B
      int v = it * 256 + t;
      int r = v >> 5, col8 = v & 31;
      *(float4*)(&UC[r][col8 * 8]) = *(const float4*)(ucb + rbase + r * DINNER + col8 * 8);
    }
  }
  __syncthreads();
  float dwreg[NST];
  #pragma unroll
  for (int r = 0; r < NST; ++r) dwreg[r] = dtw[r * DINNER + d];
  const float bias = dtb[d];
  float a2[NST];
  #pragma unroll
  for (int n = 0; n < NST; ++n) a2[n] = a2T[n * DINNER + d];
  bool geo = true;
  #pragma unroll
  for (int n = 1; n < NST; ++n)
    geo = geo && (fabsf(a2[n] - (float)(n + 1) * a2[0]) <= 1e-5f * fabsf(a2[n]));
  float S[NST];
  #pragma unroll
  for (int n = 0; n < NST; ++n) S[n] = 0.f;
  float dsum = 0.f;
  const int row0 = rbase + t;
  for (int tt = 0; tt < TCH; ++tt) {
    float acc = bias;
    #pragma unroll
    for (int r = 0; r < NST; ++r) acc = fmaf(dtsh[tt][r], dwreg[r], acc);
    float sp = (acc > 20.f) ? acc : log1pf(__expf(acc));
    unsigned short deb = f2bf(sp);
    delta_b[row0 + tt * DINNER] = deb;
    float de = bf2f(deb);                     // rounded value: exact pass-3 consistency
    float xv = bf2f(UC[tt][t]);
    float du = de * xv;
    dsum += de;
    float dA[NST];
    if (geo) {
      float r1 = exp2f(de * a2[0]);
      float p = r1;
      #pragma unroll
      for (int n = 0; n < NST; ++n) { dA[n] = p; p *= r1; }
    } else {
      #pragma unroll
      for (int n = 0; n < NST; ++n) dA[n] = exp2f(de * a2[n]);
    }
    #pragma unroll
    for (int n = 0; n < NST; ++n) S[n] = fmaf(dA[n], S[n], du * Bsh[tt][n]);
  }
  const int bc = b * NCH + c;
  Dsum[bc * DINNER + d] = dsum;
  #pragma unroll
  for (int n = 0; n < NST; ++n)
    Ssum[(size_t)((n * BATCH + b) * NCH + c) * DINNER + d] = f2bf(S[n]);
}

// ---------------------------------------------------------------- K4b: cross-chunk exclusive scan, d-coalesced (bf16 S/H)
__global__ __launch_bounds__(64) void k_scan2(const unsigned short* __restrict__ S,
                                              const float* __restrict__ Dsum,
                                              const float* __restrict__ a2T,
                                              unsigned short* __restrict__ Hinit) {
  const int idx = blockIdx.x * 64 + threadIdx.x;
  const int d  = idx & (DINNER - 1);
  const int nb = idx >> 9;
  const int b  = nb & (BATCH - 1);
  const int n  = nb >> 1;
  const float a = a2T[n * DINNER + d] * LN2;       // = -exp(A_log[d][n])
  const unsigned short* Srow = S     + (size_t)nb * NCH * DINNER + d;
  const float*          Drow = Dsum  + (size_t)b  * NCH * DINNER + d;
  unsigned short*       Hrow = Hinit + (size_t)nb * NCH * DINNER + d;
  float h = 0.f;
  #pragma unroll 8
  for (int c = 0; c < NCH; ++c) {
    float ds = Drow[(size_t)c * DINNER];
    float s  = bf2f(Srow[(size_t)c * DINNER]);
    Hrow[(size_t)c * DINNER] = f2bf(h);
    h = fmaf(__expf(a * ds), h, s);
  }
}

// ---------------------------------------------------------------- K4c: scan pass 2 + gating -> bf16 ygate (in-place over zb)
__global__ __launch_bounds__(256) void k_scan3(const unsigned short* __restrict__ ucb,
                                               const unsigned short* __restrict__ delta_b,
                                               const float* __restrict__ Bin,
                                               const float* __restrict__ Cin,
                                               const float* __restrict__ a2T,
                                               const float* __restrict__ Dvec,
                                               const unsigned short* __restrict__ Hinit,
                                               unsigned short* __restrict__ zb) {
  const int t = threadIdx.x;
  const int d0 = (blockIdx.x & 1) * 256;
  const int rest = blockIdx.x >> 1;
  const int c = rest & (NCH - 1);
  const int b = rest >> 8;
  const int d = d0 + t;
  __shared__ float Bsh[TCH][NST];
  __shared__ float Csh[TCH][NST];
  __shared__ unsigned short UC[TCH][256];
  __shared__ unsigned short DE[TCH][256];
  const int rbase = (b * LSEQ + c * TCH) * DINNER + d0;
  {
    const int base = (b * LSEQ + c * TCH) * NST;
    ((float*)Bsh)[t] = Bin[base + t];
    ((float*)Csh)[t] = Cin[base + t];
    #pragma unroll
    for (int it = 0; it < 2; ++it) {
      int v = it * 256 + t;
      int r = v >> 5, col8 = v & 31;
      *(float4*)(&UC[r][col8 * 8]) = *(const float4*)(ucb     + rbase + r * DINNER + col8 * 8);
      *(float4*)(&DE[r][col8 * 8]) = *(const float4*)(delta_b + rbase + r * DINNER + col8 * 8);
    }
  }
  __syncthreads();
  float a2[NST];
  #pragma unroll
  for (int n = 0; n < NST; ++n) a2[n] = a2T[n * DINNER + d];
  bool geo = true;
  #pragma unroll
  for (int n = 1; n < NST; ++n)
    geo = geo && (fabsf(a2[n] - (float)(n + 1) * a2[0]) <= 1e-5f * fabsf(a2[n]));
  float h[NST];
  #pragma unroll
  for (int n = 0; n < NST; ++n)
    h[n] = bf2f(Hinit[(size_t)(((n * BATCH + b) * NCH) + c) * DINNER + d]);
  const float Dd = Dvec[d];
  const int row0 = rbase + t;
  for (int tt = 0; tt < TCH; ++tt) {
    float de = bf2f(DE[tt][t]);
    float xv = bf2f(UC[tt][t]);
    float du = de * xv;
    float dA[NST];
    if (geo) {
      float r1 = exp2f(de * a2[0]);
      float p = r1;
      #pragma unroll
      for (int n = 0; n < NST; ++n) { dA[n] = p; p *= r1; }
    } else {
      #pragma unroll
      for (int n = 0; n < NST; ++n) dA[n] = exp2f(de * a2[n]);
    }
    float y = 0.f;
    #pragma unroll
    for (int n = 0; n < NST; ++n) {
      h[n] = fmaf(dA[n], h[n], du * Bsh[tt][n]);
      y = fmaf(h[n], Csh[tt][n], y);
    }
    float zz = bf2f(zb[row0 + tt * DINNER]);
    zb[row0 + tt * DINNER] = f2bf((y + xv * Dd) * fast_silu(zz));
  }
}

// ---------------------------------------------------------------- K5: out_proj (bf16 MFMA) + residual + LayerNorm
__global__ __launch_bounds__(512) void k_out(const unsigned short* __restrict__ Yb,
                                             const unsigned short* __restrict__ W2t,
                                             const float* __restrict__ X,
                                             const float* __restrict__ gam,
                                             const float* __restrict__ bet,
                                             float* __restrict__ out) {
  __shared__ unsigned short As[32][40];
  __shared__ unsigned short Bs[256][40];
  __shared__ float red[4][32][2];
  const int t = threadIdx.x;
  const int m0 = blockIdx.x * 32;
  const int lane = t & 63, wid = t >> 6;
  const int hi = lane >> 4, l15 = lane & 15;
  const int wm = wid >> 2, wn = wid & 3;
  f32x4 zero = {0.f, 0.f, 0.f, 0.f};
  f32x4 acc[4];
  #pragma unroll
  for (int bn = 0; bn < 4; ++bn) acc[bn] = zero;

  for (int k0 = 0; k0 < DINNER; k0 += 32) {
    __syncthreads();
    if (t < 128) {
      int r = t >> 2, part = t & 3;
      *(float4*)(&As[r][part * 8]) = *(const float4*)(Yb + (size_t)(m0 + r) * 512 + k0 + part * 8);
    }
    #pragma unroll
    for (int it = 0; it < 2; ++it) {
      int v = it * 512 + t;
      int r = v >> 2, part = v & 3;
      *(float4*)(&Bs[r][part * 8]) = *(const float4*)(W2t + (size_t)r * 512 + k0 + part * 8);
    }
    __syncthreads();
    bf16x8 af = *(const bf16x8*)(&As[wm * 16 + l15][hi * 8]);
    #pragma unroll
    for (int bn = 0; bn < 4; ++bn) {
      bf16x8 bfr = *(const bf16x8*)(&Bs[wn * 64 + bn * 16 + l15][hi * 8]);
      acc[bn] = __builtin_amdgcn_mfma_f32_16x16x32_bf16(af, bfr, acc[bn], 0, 0, 0);
    }
  }

  float vv[4][4];
  float s[4] = {0.f, 0.f, 0.f, 0.f}, s2[4] = {0.f, 0.f, 0.f, 0.f};
  #pragma unroll
  for (int bn = 0; bn < 4; ++bn) {
    int n = wn * 64 + bn * 16 + l15;
    #pragma unroll
    for (int j = 0; j < 4; ++j) {
      int m = m0 + wm * 16 + hi * 4 + j;
      float v = acc[bn][j] + X[(size_t)m * DMODEL + n];
      vv[bn][j] = v;
      s[j] += v; s2[j] += v * v;
    }
  }
  #pragma unroll
  for (int j = 0; j < 4; ++j) {
    #pragma unroll
    for (int off = 1; off < 16; off <<= 1) {
      s[j]  += __shfl_xor(s[j],  off, 64);
      s2[j] += __shfl_xor(s2[j], off, 64);
    }
  }
  if (l15 == 0) {
    #pragma unroll
    for (int j = 0; j < 4; ++j) {
      red[wn][wm * 16 + hi * 4 + j][0] = s[j];
      red[wn][wm * 16 + hi * 4 + j][1] = s2[j];
    }
  }
  __syncthreads();
  float g[4], bb[4];
  #pragma unroll
  for (int bn = 0; bn < 4; ++bn) {
    int n = wn * 64 + bn * 16 + l15;
    g[bn] = gam[n]; bb[bn] = bet[n];
  }
  #pragma unroll
  for (int j = 0; j < 4; ++j) {
    int row = wm * 16 + hi * 4 + j;
    float S  = red[0][row][0] + red[1][row][0] + red[2][row][0] + red[3][row][0];
    float S2 = red[0][row][1] + red[1][row][1] + red[2][row][1] + red[3][row][1];
    float mu = S * (1.f / 256.f);
    float rstd = rsqrtf(S2 * (1.f / 256.f) - mu * mu + 1e-5f);
    int m = m0 + row;
    #pragma unroll
    for (int bn = 0; bn < 4; ++bn) {
      int n = wn * 64 + bn * 16 + l15;
      out[(size_t)m * DMODEL + n] = (vv[bn][j] - mu) * rstd * g[bn] + bb[bn];
    }
  }
}

// ----------------------------------------------------------------
extern "C" void kernel_launch(void* const* d_in, const int* in_sizes, int n_in,
                              void* d_out, int out_size, void* d_ws, size_t ws_size,
                              hipStream_t stream) {
  const float* x    = (const float*)d_in[0];
  const float* ipw  = (const float*)d_in[1];
  const float* cw   = (const float*)d_in[2];
  const float* cb   = (const float*)d_in[3];
  const float* xpw  = (const float*)d_in[4];
  const float* dtw  = (const float*)d_in[5];
  const float* dtbv = (const float*)d_in[6];
  const float* alog = (const float*)d_in[7];
  const float* Dv   = (const float*)d_in[8];
  const float* opw  = (const float*)d_in[9];
  const float* gam  = (const float*)d_in[10];
  const float* bet  = (const float*)d_in[11];
  float* out = (float*)d_out;

  char* ws = (char*)d_ws;
  unsigned short* ub  = (unsigned short*)ws;   ws += (size_t)MROWS * DINNER * 2;  // u bf16; reused as delta
  unsigned short* zb  = (unsigned short*)ws;   ws += (size_t)MROWS * DINNER * 2;  // z bf16; in-place ygate
  unsigned short* ucb = (unsigned short*)ws;   ws += (size_t)MROWS * DINNER * 2;  // conv(u) bf16
  float* buf_dt = (float*)ws;  ws += (size_t)MROWS * NST * 4;
  float* buf_B  = (float*)ws;  ws += (size_t)MROWS * NST * 4;
  float* buf_C  = (float*)ws;  ws += (size_t)MROWS * NST * 4;
  float* buf_ds = (float*)ws;  ws += (size_t)BATCH * NCH * DINNER * 4;            // Dsum fp32
  unsigned short* buf_S = (unsigned short*)ws;  ws += (size_t)NST * BATCH * NCH * DINNER * 2;  // Ssum bf16
  unsigned short* buf_H = (unsigned short*)ws;  ws += (size_t)NST * BATCH * NCH * DINNER * 2;  // Hinit bf16
  unsigned short* W1t = (unsigned short*)ws; ws += (size_t)1024 * 256 * 2;
  unsigned short* W2t = (unsigned short*)ws; ws += (size_t)256 * 512 * 2;
  unsigned short* xpT = (unsigned short*)ws; ws += (size_t)48 * 512 * 2;
  float* a2T = (float*)ws;     ws += (size_t)NST * DINNER * 4;                    // -exp(A_log)^T * log2e
  unsigned short* deltab = ub;                 // alias: u dead after k_conv

  k_castT   <<<dim3(256),  dim3(256), 0, stream>>>(ipw, W1t, 256, 1024, 8);
  k_castT   <<<dim3(128),  dim3(256), 0, stream>>>(opw, W2t, 512, 256, 16);
  k_cast_xpw<<<dim3(96),   dim3(256), 0, stream>>>(xpw, xpT);
  k_prep_a2 <<<dim3(32),   dim3(256), 0, stream>>>(alog, a2T);
  k_inproj  <<<dim3(512),  dim3(256), 0, stream>>>(x, W1t, ub, zb);
  k_conv    <<<dim3(MROWS * DINNER / 512), dim3(256), 0, stream>>>(ub, cw, cb, ucb);
  k_xprojm  <<<dim3(MROWS / 32), dim3(128), 0, stream>>>(ucb, xpT, buf_dt, buf_B, buf_C);
  k_scan1   <<<dim3(BATCH * NCH * DINNER / 256), dim3(256), 0, stream>>>(ucb, buf_dt, dtw, dtbv, buf_B,
                                                                         a2T, deltab, buf_S, buf_ds);
  k_scan2   <<<dim3(NST * BATCH * DINNER / 64), dim3(64), 0, stream>>>(buf_S, buf_ds, a2T, buf_H);
  k_scan3   <<<dim3(BATCH * NCH * DINNER / 256), dim3(256), 0, stream>>>(ucb, deltab, buf_B, buf_C,
                                                                         a2T, Dv, buf_H, zb);
  k_out     <<<dim3(MROWS / 32), dim3(512), 0, stream>>>(zb, W2t, x, gam, bet, out);
}

// Round 12
// 111.015 us; speedup vs baseline: 1.2130x; 1.2130x over previous
//
#include <hip/hip_runtime.h>
#include <math.h>

constexpr int BATCH  = 2;
constexpr int LSEQ   = 4096;
constexpr int DMODEL = 256;
constexpr int DINNER = 512;
constexpr int NST    = 16;              // d_state
constexpr int MROWS  = BATCH * LSEQ;    // 8192
constexpr int NCH    = 256;             // chunks per sequence
constexpr int TCH    = LSEQ / NCH;      // 16 steps per chunk
constexpr float LOG2E = 1.44269504088896f;
constexpr float LN2   = 0.69314718056f;

typedef __attribute__((ext_vector_type(8))) short bf16x8;
typedef __attribute__((ext_vector_type(4))) float f32x4;

__device__ __forceinline__ float fast_silu(float v) { return v / (1.f + __expf(-v)); }

__device__ __forceinline__ unsigned short f2bf(float f) {
  unsigned int u = __float_as_uint(f);
  u = (u + 0x7fffu + ((u >> 16) & 1u)) >> 16;   // RNE
  return (unsigned short)u;
}
__device__ __forceinline__ float bf2f(unsigned short u) {
  return __uint_as_float(((unsigned int)u) << 16);
}

// ---------------------------------------------------------------- merged prep: weight transpose-casts + a2T
// blocks [0,256): ipw->W1t; [256,384): opw->W2t; [384,480): xpw->xpT; [480,512): a2T
__global__ __launch_bounds__(256) void k_prep(const float* __restrict__ ipw,
                                              const float* __restrict__ opw,
                                              const float* __restrict__ xpw,
                                              const float* __restrict__ Alog,
                                              unsigned short* __restrict__ W1t,
                                              unsigned short* __restrict__ W2t,
                                              unsigned short* __restrict__ xpT,
                                              float* __restrict__ a2T) {
  __shared__ float tile[32][33];
  const int bid = blockIdx.x;
  const int t = threadIdx.x;
  if (bid < 384) {
    const float* W; unsigned short* Wt; int K, N, ktiles, bt;
    if (bid < 256) { W = ipw; Wt = W1t; K = 256; N = 1024; ktiles = 8;  bt = bid; }
    else           { W = opw; Wt = W2t; K = 512; N = 256;  ktiles = 16; bt = bid - 256; }
    const int kt = bt % ktiles, nt = bt / ktiles;
    const int k0 = kt * 32, n0 = nt * 32;
    const int c = t & 31, r0 = t >> 5;
    #pragma unroll
    for (int it = 0; it < 4; ++it) {
      int r = r0 + it * 8;
      tile[r][c] = W[(size_t)(k0 + r) * N + n0 + c];
    }
    __syncthreads();
    #pragma unroll
    for (int it = 0; it < 4; ++it) {
      int cc = r0 + it * 8;
      Wt[(size_t)(n0 + cc) * K + k0 + c] = f2bf(tile[c][cc]);
    }
  } else if (bid < 480) {
    int idx = (bid - 384) * 256 + t;     // 48*512
    int n = idx >> 9, k = idx & 511;
    xpT[n * 512 + k] = f2bf(xpw[k * 48 + n]);
  } else {
    int idx = (bid - 480) * 256 + t;     // 16*512
    int n = idx >> 9, d = idx & 511;
    a2T[idx] = -__expf(Alog[d * NST + n]) * LOG2E;
  }
}

// ---------------------------------------------------------------- K1: xz = x @ in_proj_w (bf16 MFMA); u,z bf16
__global__ __launch_bounds__(256) void k_inproj(const float* __restrict__ X,
                                                const unsigned short* __restrict__ Wt,
                                                unsigned short* __restrict__ ub,
                                                unsigned short* __restrict__ zb) {
  __shared__ unsigned short As[128][40];
  __shared__ unsigned short Bs[128][40];
  const int t = threadIdx.x;
  const int m0 = (blockIdx.x & 63) * 128;
  const int n0 = (blockIdx.x >> 6) * 128;
  const int lane = t & 63, wid = t >> 6;
  const int hi = lane >> 4, l15 = lane & 15;
  const int wm = wid >> 1, wn = wid & 1;
  f32x4 zero = {0.f, 0.f, 0.f, 0.f};
  f32x4 acc[4][4];
  #pragma unroll
  for (int i = 0; i < 4; ++i)
    #pragma unroll
    for (int j = 0; j < 4; ++j) acc[i][j] = zero;

  for (int k0 = 0; k0 < DMODEL; k0 += 32) {
    __syncthreads();
    #pragma unroll
    for (int it = 0; it < 4; ++it) {              // A: fp32 -> bf16 during stage
      int v = it * 256 + t;
      int r = v >> 3, part = v & 7;
      float4 a = *(const float4*)(X + (size_t)(m0 + r) * 256 + k0 + part * 4);
      ushort4 o;
      o.x = f2bf(a.x); o.y = f2bf(a.y); o.z = f2bf(a.z); o.w = f2bf(a.w);
      *(ushort4*)(&As[r][part * 4]) = o;
    }
    #pragma unroll
    for (int it = 0; it < 2; ++it) {              // B: bf16 direct
      int v = it * 256 + t;
      int r = v >> 2, part = v & 3;
      *(float4*)(&Bs[r][part * 8]) = *(const float4*)(Wt + (size_t)(n0 + r) * 256 + k0 + part * 8);
    }
    __syncthreads();
    bf16x8 af[4], bfv[4];
    #pragma unroll
    for (int am = 0; am < 4; ++am) af[am] = *(const bf16x8*)(&As[wm * 64 + am * 16 + l15][hi * 8]);
    #pragma unroll
    for (int bn = 0; bn < 4; ++bn) bfv[bn] = *(const bf16x8*)(&Bs[wn * 64 + bn * 16 + l15][hi * 8]);
    #pragma unroll
    for (int am = 0; am < 4; ++am)
      #pragma unroll
      for (int bn = 0; bn < 4; ++bn)
        acc[am][bn] = __builtin_amdgcn_mfma_f32_16x16x32_bf16(af[am], bfv[bn], acc[am][bn], 0, 0, 0);
  }

  unsigned short* dst = (n0 < DINNER) ? ub : zb;
  const int nb = (n0 < DINNER) ? n0 : n0 - DINNER;
  #pragma unroll
  for (int am = 0; am < 4; ++am)
    #pragma unroll
    for (int j = 0; j < 4; ++j) {
      int m = m0 + wm * 64 + am * 16 + hi * 4 + j;
      #pragma unroll
      for (int bn = 0; bn < 4; ++bn) {
        int n = nb + wn * 64 + bn * 16 + l15;
        dst[(size_t)m * DINNER + n] = f2bf(acc[am][bn][j]);
      }
    }
}

// ---------------------------------------------------------------- K2+K3 fused: conv+SiLU (in LDS) -> ucb + xproj MFMA
// block = 32 rows; stages ub rows m0-3..m0+31, conv in-place, writes ucb, then MFMA vs xpT
__global__ __launch_bounds__(128) void k_xprojm(const unsigned short* __restrict__ ub,
                                                const float* __restrict__ cw,
                                                const float* __restrict__ cb,
                                                unsigned short* __restrict__ ucb,
                                                const unsigned short* __restrict__ xpT,
                                                float* __restrict__ dt_out,
                                                float* __restrict__ Bout,
                                                float* __restrict__ Cout) {
  __shared__ unsigned short U[35][520];    // rows m0-3..m0+31; conv output lands in rows 3..34
  __shared__ unsigned short Bs[48][136];
  const int t = threadIdx.x;
  const int m0 = blockIdx.x * 32;
  const int l0 = m0 & (LSEQ - 1);
  const int lane = t & 63, wid = t >> 6;   // 2 waves
  const int hi = lane >> 4, l15 = lane & 15;

  // stage u tile (35 rows x 512 cols bf16), zero-pad causal rows
  for (int v = t; v < 35 * 64; v += 128) {
    int r = v >> 6, c8 = v & 63;
    float4 val = {0.f, 0.f, 0.f, 0.f};
    if (l0 - 3 + r >= 0)
      val = *(const float4*)(ub + (size_t)(m0 - 3 + r) * 512 + c8 * 8);
    *(float4*)(&U[r][c8 * 8]) = val;
  }
  __syncthreads();

  // depthwise conv + SiLU, in-place: output row r (of 32) overwrites U[r+3]; descending r is safe
  #pragma unroll
  for (int cc = 0; cc < 4; ++cc) {
    const int k = t * 4 + cc;              // 128*4 = 512 columns, thread-exclusive
    const float w0 = cw[k * 4 + 0], w1 = cw[k * 4 + 1], w2 = cw[k * 4 + 2], w3 = cw[k * 4 + 3];
    const float bias = cb[k];
    for (int r = 31; r >= 0; --r) {
      float acc = bias;
      acc = fmaf(bf2f(U[r + 0][k]), w0, acc);
      acc = fmaf(bf2f(U[r + 1][k]), w1, acc);
      acc = fmaf(bf2f(U[r + 2][k]), w2, acc);
      acc = fmaf(bf2f(U[r + 3][k]), w3, acc);
      U[r + 3][k] = f2bf(fast_silu(acc));
    }
  }
  __syncthreads();

  // write ucb (rows 0..31 = U[3..34])
  for (int v = t; v < 32 * 64; v += 128) {
    int r = v >> 6, c8 = v & 63;
    *(float4*)(ucb + (size_t)(m0 + r) * 512 + c8 * 8) = *(const float4*)(&U[r + 3][c8 * 8]);
  }

  // MFMA: dbl = uc @ xpT^T
  f32x4 zero = {0.f, 0.f, 0.f, 0.f};
  f32x4 acc[3] = {zero, zero, zero};
  for (int k0 = 0; k0 < DINNER; k0 += 128) {
    __syncthreads();
    #pragma unroll
    for (int it = 0; it < 6; ++it) {
      int v = it * 128 + t;
      int r = v >> 4, part = v & 15;
      *(float4*)(&Bs[r][part * 8]) = *(const float4*)(xpT + (size_t)r * 512 + k0 + part * 8);
    }
    __syncthreads();
    #pragma unroll
    for (int kk = 0; kk < 4; ++kk) {
      bf16x8 af = *(const bf16x8*)(&U[3 + wid * 16 + l15][k0 + kk * 32 + hi * 8]);
      #pragma unroll
      for (int nf = 0; nf < 3; ++nf) {
        bf16x8 bv = *(const bf16x8*)(&Bs[nf * 16 + l15][kk * 32 + hi * 8]);
        acc[nf] = __builtin_amdgcn_mfma_f32_16x16x32_bf16(af, bv, acc[nf], 0, 0, 0);
      }
    }
  }
  #pragma unroll
  for (int j = 0; j < 4; ++j) {
    int m = m0 + wid * 16 + hi * 4 + j;
    dt_out[m * 16 + l15] = acc[0][j];
    Bout[m * 16 + l15]   = acc[1][j];
    Cout[m * 16 + l15]   = acc[2][j];
  }
}

// ---------------------------------------------------------------- K4a: scan pass 1: delta (bf16) + per-chunk (S bf16, dsum)
__global__ __launch_bounds__(256) void k_scan1(const unsigned short* __restrict__ ucb,
                                               const float* __restrict__ dtin,
                                               const float* __restrict__ dtw,
                                               const float* __restrict__ dtb,
                                               const float* __restrict__ Bin,
                                               const float* __restrict__ a2T,
                                               unsigned short* __restrict__ delta_b,
                                               unsigned short* __restrict__ Ssum,
                                               float* __restrict__ Dsum) {
  const int t = threadIdx.x;
  const int d0 = (blockIdx.x & 1) * 256;
  const int rest = blockIdx.x >> 1;
  const int c = rest & (NCH - 1);
  const int b = rest >> 8;
  const int d = d0 + t;
  __shared__ float Bsh[TCH][NST];
  __shared__ float dtsh[TCH][NST];
  __shared__ unsigned short UC[TCH][256];
  const int rbase = (b * LSEQ + c * TCH) * DINNER + d0;
  {
    const int base = (b * LSEQ + c * TCH) * NST;
    ((float*)Bsh)[t]  = Bin[base + t];             // TCH*NST == 256
    ((float*)dtsh)[t] = dtin[base + t];
    #pragma unroll
    for (int it = 0; it < 2; ++it) {
      int v = it * 256 + t;
      int r = v >> 5, col8 = v & 31;
      *(float4*)(&UC[r][col8 * 8]) = *(const float4*)(ucb + rbase + r * DINNER + col8 * 8);
    }
  }
  __syncthreads();
  float dwreg[NST];
  #pragma unroll
  for (int r = 0; r < NST; ++r) dwreg[r] = dtw[r * DINNER + d];
  const float bias = dtb[d];
  float a2[NST];
  #pragma unroll
  for (int n = 0; n < NST; ++n) a2[n] = a2T[n * DINNER + d];
  bool geo = true;
  #pragma unroll
  for (int n = 1; n < NST; ++n)
    geo = geo && (fabsf(a2[n] - (float)(n + 1) * a2[0]) <= 1e-5f * fabsf(a2[n]));
  float S[NST];
  #pragma unroll
  for (int n = 0; n < NST; ++n) S[n] = 0.f;
  float dsum = 0.f;
  const int row0 = rbase + t;
  for (int tt = 0; tt < TCH; ++tt) {
    float acc = bias;
    #pragma unroll
    for (int r = 0; r < NST; ++r) acc = fmaf(dtsh[tt][r], dwreg[r], acc);
    float sp = (acc > 20.f) ? acc : __logf(1.f + __expf(acc));   // fast softplus (bf16-safe)
    unsigned short deb = f2bf(sp);
    delta_b[row0 + tt * DINNER] = deb;
    float de = bf2f(deb);                     // rounded value: exact pass-3 consistency
    float xv = bf2f(UC[tt][t]);
    float du = de * xv;
    dsum += de;
    float dA[NST];
    if (geo) {
      float r1 = exp2f(de * a2[0]);
      float p = r1;
      #pragma unroll
      for (int n = 0; n < NST; ++n) { dA[n] = p; p *= r1; }
    } else {
      #pragma unroll
      for (int n = 0; n < NST; ++n) dA[n] = exp2f(de * a2[n]);
    }
    #pragma unroll
    for (int n = 0; n < NST; ++n) S[n] = fmaf(dA[n], S[n], du * Bsh[tt][n]);
  }
  const int bc = b * NCH + c;
  Dsum[bc * DINNER + d] = dsum;
  #pragma unroll
  for (int n = 0; n < NST; ++n)
    Ssum[(size_t)((n * BATCH + b) * NCH + c) * DINNER + d] = f2bf(S[n]);
}

// ---------------------------------------------------------------- K4b: cross-chunk exclusive scan, d-coalesced (bf16 S/H)
__global__ __launch_bounds__(64) void k_scan2(const unsigned short* __restrict__ S,
                                              const float* __restrict__ Dsum,
                                              const float* __restrict__ a2T,
                                              unsigned short* __restrict__ Hinit) {
  const int idx = blockIdx.x * 64 + threadIdx.x;
  const int d  = idx & (DINNER - 1);
  const int nb = idx >> 9;
  const int b  = nb & (BATCH - 1);
  const int n  = nb >> 1;
  const float a = a2T[n * DINNER + d] * LN2;       // = -exp(A_log[d][n])
  const unsigned short* Srow = S     + (size_t)nb * NCH * DINNER + d;
  const float*          Drow = Dsum  + (size_t)b  * NCH * DINNER + d;
  unsigned short*       Hrow = Hinit + (size_t)nb * NCH * DINNER + d;
  float h = 0.f;
  #pragma unroll 8
  for (int c = 0; c < NCH; ++c) {
    float ds = Drow[(size_t)c * DINNER];
    float s  = bf2f(Srow[(size_t)c * DINNER]);
    Hrow[(size_t)c * DINNER] = f2bf(h);
    h = fmaf(__expf(a * ds), h, s);
  }
}

// ---------------------------------------------------------------- K4c: scan pass 2 + gating -> bf16 ygate (in-place over zb)
__global__ __launch_bounds__(256) void k_scan3(const unsigned short* __restrict__ ucb,
                                               const unsigned short* __restrict__ delta_b,
                                               const float* __restrict__ Bin,
                                               const float* __restrict__ Cin,
                                               const float* __restrict__ a2T,
                                               const float* __restrict__ Dvec,
                                               const unsigned short* __restrict__ Hinit,
                                               unsigned short* __restrict__ zb) {
  const int t = threadIdx.x;
  const int d0 = (blockIdx.x & 1) * 256;
  const int rest = blockIdx.x >> 1;
  const int c = rest & (NCH - 1);
  const int b = rest >> 8;
  const int d = d0 + t;
  __shared__ float Bsh[TCH][NST];
  __shared__ float Csh[TCH][NST];
  __shared__ unsigned short UC[TCH][256];
  __shared__ unsigned short DE[TCH][256];
  const int rbase = (b * LSEQ + c * TCH) * DINNER + d0;
  {
    const int base = (b * LSEQ + c * TCH) * NST;
    ((float*)Bsh)[t] = Bin[base + t];
    ((float*)Csh)[t] = Cin[base + t];
    #pragma unroll
    for (int it = 0; it < 2; ++it) {
      int v = it * 256 + t;
      int r = v >> 5, col8 = v & 31;
      *(float4*)(&UC[r][col8 * 8]) = *(const float4*)(ucb     + rbase + r * DINNER + col8 * 8);
      *(float4*)(&DE[r][col8 * 8]) = *(const float4*)(delta_b + rbase + r * DINNER + col8 * 8);
    }
  }
  __syncthreads();
  float a2[NST];
  #pragma unroll
  for (int n = 0; n < NST; ++n) a2[n] = a2T[n * DINNER + d];
  bool geo = true;
  #pragma unroll
  for (int n = 1; n < NST; ++n)
    geo = geo && (fabsf(a2[n] - (float)(n + 1) * a2[0]) <= 1e-5f * fabsf(a2[n]));
  float h[NST];
  #pragma unroll
  for (int n = 0; n < NST; ++n)
    h[n] = bf2f(Hinit[(size_t)(((n * BATCH + b) * NCH) + c) * DINNER + d]);
  const float Dd = Dvec[d];
  const int row0 = rbase + t;
  for (int tt = 0; tt < TCH; ++tt) {
    float de = bf2f(DE[tt][t]);
    float xv = bf2f(UC[tt][t]);
    float du = de * xv;
    float dA[NST];
    if (geo) {
      float r1 = exp2f(de * a2[0]);
      float p = r1;
      #pragma unroll
      for (int n = 0; n < NST; ++n) { dA[n] = p; p *= r1; }
    } else {
      #pragma unroll
      for (int n = 0; n < NST; ++n) dA[n] = exp2f(de * a2[n]);
    }
    float y = 0.f;
    #pragma unroll
    for (int n = 0; n < NST; ++n) {
      h[n] = fmaf(dA[n], h[n], du * Bsh[tt][n]);
      y = fmaf(h[n], Csh[tt][n], y);
    }
    float zz = bf2f(zb[row0 + tt * DINNER]);
    zb[row0 + tt * DINNER] = f2bf((y + xv * Dd) * fast_silu(zz));
  }
}

// ---------------------------------------------------------------- K5: out_proj (bf16 MFMA) + residual + LayerNorm
__global__ __launch_bounds__(512) void k_out(const unsigned short* __restrict__ Yb,
                                             const unsigned short* __restrict__ W2t,
                                             const float* __restrict__ X,
                                             const float* __restrict__ gam,
                                             const float* __restrict__ bet,
                                             float* __restrict__ out) {
  __shared__ unsigned short As[32][40];
  __shared__ unsigned short Bs[256][40];
  __shared__ float red[4][32][2];
  const int t = threadIdx.x;
  const int m0 = blockIdx.x * 32;
  const int lane = t & 63, wid = t >> 6;
  const int hi = lane >> 4, l15 = lane & 15;
  const int wm = wid >> 2, wn = wid & 3;
  f32x4 zero = {0.f, 0.f, 0.f, 0.f};
  f32x4 acc[4];
  #pragma unroll
  for (int bn = 0; bn < 4; ++bn) acc[bn] = zero;

  for (int k0 = 0; k0 < DINNER; k0 += 32) {
    __syncthreads();
    if (t < 128) {
      int r = t >> 2, part = t & 3;
      *(float4*)(&As[r][part * 8]) = *(const float4*)(Yb + (size_t)(m0 + r) * 512 + k0 + part * 8);
    }
    #pragma unroll
    for (int it = 0; it < 2; ++it) {
      int v = it * 512 + t;
      int r = v >> 2, part = v & 3;
      *(float4*)(&Bs[r][part * 8]) = *(const float4*)(W2t + (size_t)r * 512 + k0 + part * 8);
    }
    __syncthreads();
    bf16x8 af = *(const bf16x8*)(&As[wm * 16 + l15][hi * 8]);
    #pragma unroll
    for (int bn = 0; bn < 4; ++bn) {
      bf16x8 bfr = *(const bf16x8*)(&Bs[wn * 64 + bn * 16 + l15][hi * 8]);
      acc[bn] = __builtin_amdgcn_mfma_f32_16x16x32_bf16(af, bfr, acc[bn], 0, 0, 0);
    }
  }

  float vv[4][4];
  float s[4] = {0.f, 0.f, 0.f, 0.f}, s2[4] = {0.f, 0.f, 0.f, 0.f};
  #pragma unroll
  for (int bn = 0; bn < 4; ++bn) {
    int n = wn * 64 + bn * 16 + l15;
    #pragma unroll
    for (int j = 0; j < 4; ++j) {
      int m = m0 + wm * 16 + hi * 4 + j;
      float v = acc[bn][j] + X[(size_t)m * DMODEL + n];
      vv[bn][j] = v;
      s[j] += v; s2[j] += v * v;
    }
  }
  #pragma unroll
  for (int j = 0; j < 4; ++j) {
    #pragma unroll
    for (int off = 1; off < 16; off <<= 1) {
      s[j]  += __shfl_xor(s[j],  off, 64);
      s2[j] += __shfl_xor(s2[j], off, 64);
    }
  }
  if (l15 == 0) {
    #pragma unroll
    for (int j = 0; j < 4; ++j) {
      red[wn][wm * 16 + hi * 4 + j][0] = s[j];
      red[wn][wm * 16 + hi * 4 + j][1] = s2[j];
    }
  }
  __syncthreads();
  float g[4], bb[4];
  #pragma unroll
  for (int bn = 0; bn < 4; ++bn) {
    int n = wn * 64 + bn * 16 + l15;
    g[bn] = gam[n]; bb[bn] = bet[n];
  }
  #pragma unroll
  for (int j = 0; j < 4; ++j) {
    int row = wm * 16 + hi * 4 + j;
    float S  = red[0][row][0] + red[1][row][0] + red[2][row][0] + red[3][row][0];
    float S2 = red[0][row][1] + red[1][row][1] + red[2][row][1] + red[3][row][1];
    float mu = S * (1.f / 256.f);
    float rstd = rsqrtf(S2 * (1.f / 256.f) - mu * mu + 1e-5f);
    int m = m0 + row;
    #pragma unroll
    for (int bn = 0; bn < 4; ++bn) {
      int n = wn * 64 + bn * 16 + l15;
      out[(size_t)m * DMODEL + n] = (vv[bn][j] - mu) * rstd * g[bn] + bb[bn];
    }
  }
}

// ----------------------------------------------------------------
extern "C" void kernel_launch(void* const* d_in, const int* in_sizes, int n_in,
                              void* d_out, int out_size, void* d_ws, size_t ws_size,
                              hipStream_t stream) {
  const float* x    = (const float*)d_in[0];
  const float* ipw  = (const float*)d_in[1];
  const float* cw   = (const float*)d_in[2];
  const float* cb   = (const float*)d_in[3];
  const float* xpw  = (const float*)d_in[4];
  const float* dtw  = (const float*)d_in[5];
  const float* dtbv = (const float*)d_in[6];
  const float* alog = (const float*)d_in[7];
  const float* Dv   = (const float*)d_in[8];
  const float* opw  = (const float*)d_in[9];
  const float* gam  = (const float*)d_in[10];
  const float* bet  = (const float*)d_in[11];
  float* out = (float*)d_out;

  char* ws = (char*)d_ws;
  unsigned short* ub  = (unsigned short*)ws;   ws += (size_t)MROWS * DINNER * 2;  // u bf16; reused as delta
  unsigned short* zb  = (unsigned short*)ws;   ws += (size_t)MROWS * DINNER * 2;  // z bf16; in-place ygate
  unsigned short* ucb = (unsigned short*)ws;   ws += (size_t)MROWS * DINNER * 2;  // conv(u) bf16
  float* buf_dt = (float*)ws;  ws += (size_t)MROWS * NST * 4;
  float* buf_B  = (float*)ws;  ws += (size_t)MROWS * NST * 4;
  float* buf_C  = (float*)ws;  ws += (size_t)MROWS * NST * 4;
  float* buf_ds = (float*)ws;  ws += (size_t)BATCH * NCH * DINNER * 4;            // Dsum fp32
  unsigned short* buf_S = (unsigned short*)ws;  ws += (size_t)NST * BATCH * NCH * DINNER * 2;  // Ssum bf16
  unsigned short* buf_H = (unsigned short*)ws;  ws += (size_t)NST * BATCH * NCH * DINNER * 2;  // Hinit bf16
  unsigned short* W1t = (unsigned short*)ws; ws += (size_t)1024 * 256 * 2;
  unsigned short* W2t = (unsigned short*)ws; ws += (size_t)256 * 512 * 2;
  unsigned short* xpT = (unsigned short*)ws; ws += (size_t)48 * 512 * 2;
  float* a2T = (float*)ws;     ws += (size_t)NST * DINNER * 4;                    // -exp(A_log)^T * log2e
  unsigned short* deltab = ub;                 // alias: u dead after k_xprojm

  k_prep   <<<dim3(512),  dim3(256), 0, stream>>>(ipw, opw, xpw, alog, W1t, W2t, xpT, a2T);
  k_inproj <<<dim3(512),  dim3(256), 0, stream>>>(x, W1t, ub, zb);
  k_xprojm <<<dim3(MROWS / 32), dim3(128), 0, stream>>>(ub, cw, cb, ucb, xpT, buf_dt, buf_B, buf_C);
  k_scan1  <<<dim3(BATCH * NCH * 2), dim3(256), 0, stream>>>(ucb, buf_dt, dtw, dtbv, buf_B,
                                                             a2T, deltab, buf_S, buf_ds);
  k_scan2  <<<dim3(NST * BATCH * DINNER / 64), dim3(64), 0, stream>>>(buf_S, buf_ds, a2T, buf_H);
  k_scan3  <<<dim3(BATCH * NCH * 2), dim3(256), 0, stream>>>(ucb, deltab, buf_B, buf_C,
                                                             a2T, Dv, buf_H, zb);
  k_out    <<<dim3(MROWS / 32), dim3(512), 0, stream>>>(zb, W2t, x, gam, bet, out);
}